// Round 1
// baseline (200.924 us; speedup 1.0000x reference)
//
#include <hip/hip_runtime.h>
#include <math.h>

#define LR 0.001f

// Sizes
#define B   64
#define IN  2048
#define HID 512
#define OUT 128

// ws layout (floats)
//  z      @ 0       (32768)  accum, zero-init
//  zo     @ 32768   (8192)   accum, zero-init
//  tanhv  @ 40960   (32768)
//  gb2    @ 73728   (8192)
//  gb     @ 81920   (32768)
#define WS_Z     0
#define WS_ZO    32768
#define WS_TANH  40960
#define WS_GB2   73728
#define WS_GB    81920

// out layout (floats)
#define O_L2N   0
#define O_DW0   8192
#define O_DB0   67117056
#define O_DW1   67149824
#define O_DB1   71344128

// ---- layer-1 forward partials: z[b,h] += sum_q x[b,q]*(W0[q,h]+dW0[b,q,h])
// grid (B, 32), block 128; each thread owns 4 h (float4), each block 64 q rows.
__global__ void k_fwd1(const float* __restrict__ x, const float* __restrict__ W0,
                       const float* __restrict__ dW0, float* __restrict__ z) {
    const int b = blockIdx.x;
    const int q0 = blockIdx.y * 64;
    const int h = threadIdx.x * 4;        // 0..508
    const float* xr = x + b * IN;
    float4 acc = make_float4(0.f, 0.f, 0.f, 0.f);
    for (int qi = 0; qi < 64; ++qi) {
        const int q = q0 + qi;
        const float xv = xr[q];
        const float4 w0 = *(const float4*)(W0 + q * HID + h);
        const float4 dw = *(const float4*)(dW0 + ((size_t)(b * IN + q)) * HID + h);
        acc.x += xv * (w0.x + dw.x);
        acc.y += xv * (w0.y + dw.y);
        acc.z += xv * (w0.z + dw.z);
        acc.w += xv * (w0.w + dw.w);
    }
    float* zp = z + b * HID + h;
    atomicAdd(zp + 0, acc.x);
    atomicAdd(zp + 1, acc.y);
    atomicAdd(zp + 2, acc.z);
    atomicAdd(zp + 3, acc.w);
}

// ---- tanh(z + b0 + db0)
__global__ void k_tanh(const float* __restrict__ z, const float* __restrict__ b0,
                       const float* __restrict__ db0, float* __restrict__ tanhv) {
    const int i = blockIdx.x * blockDim.x + threadIdx.x;   // 32768 total
    const float v = z[i] + b0[i & (HID - 1)] + db0[i];
    tanhv[i] = tanhf(v);
}

// ---- layer-2 forward partials: zo[b,o] += sum_h tanh[b,h]*(W1[h,o]+dW1[b,h,o])
// grid (B, 8), block 128 (one o per thread), each block 64 h rows.
__global__ void k_fwd2(const float* __restrict__ tanhv, const float* __restrict__ W1,
                       const float* __restrict__ dW1, float* __restrict__ zo) {
    const int b = blockIdx.x;
    const int h0 = blockIdx.y * 64;
    const int o = threadIdx.x;
    float acc = 0.f;
    for (int hi = 0; hi < 64; ++hi) {
        const int h = h0 + hi;
        const float th = tanhv[b * HID + h];
        acc += th * (W1[h * OUT + o] + dW1[(b * HID + h) * OUT + o]);
    }
    atomicAdd(&zo[b * OUT + o], acc);
}

// ---- middle: out2, l2, t-normalize, g_b2, l2_normed_out2, new_d_bias_1
// grid B, block 128 (=OUT)
__global__ void k_mid(const float* __restrict__ zo, const float* __restrict__ b1,
                      const float* __restrict__ db1, const float* __restrict__ ut,
                      float* __restrict__ out_l2n, float* __restrict__ out_db1,
                      float* __restrict__ gb2) {
    const int b = blockIdx.x;
    const int o = threadIdx.x;
    const int i = b * OUT + o;
    const float out2v = zo[i] + b1[o] + db1[i];
    const float tr = ut[i];
    float a = out2v * out2v;
    float c = tr * tr;
    float d = tr * out2v;
    for (int off = 32; off; off >>= 1) {
        a += __shfl_xor(a, off, 64);
        c += __shfl_xor(c, off, 64);
        d += __shfl_xor(d, off, 64);
    }
    __shared__ float s[3][2];
    const int w = threadIdx.x >> 6;
    if ((threadIdx.x & 63) == 0) { s[0][w] = a; s[1][w] = c; s[2][w] = d; }
    __syncthreads();
    const float l2 = s[0][0] + s[0][1];                       // squared norm (as in source)
    const float nt = fmaxf(sqrtf(s[1][0] + s[1][1]), 1e-12f); // ||update_target||
    const float tdot = (s[2][0] + s[2][1]) / nt;              // sum(t * out2)
    const float tn = tr / nt;
    const float g2 = -tn / l2 + (tdot / (l2 * l2)) * 2.0f * out2v;
    out_l2n[i] = out2v / l2;
    out_db1[i] = db1[i] - LR * g2;
    gb2[i] = g2;
}

// ---- backward through layer 2: g_b + new_d_weights_1 + new_d_bias_0
// grid (B, 8), block 256 (4 waves); each wave owns 16 h rows; lane owns 2 o.
__global__ void k_bwd1(const float* __restrict__ W1, const float* __restrict__ dW1,
                       const float* __restrict__ gb2, const float* __restrict__ tanhv,
                       const float* __restrict__ db0,
                       float* __restrict__ out_dW1, float* __restrict__ out_db0,
                       float* __restrict__ gb) {
    const int b = blockIdx.x;
    const int w = threadIdx.x >> 6;
    const int lane = threadIdx.x & 63;
    const int o2 = lane * 2;
    const float2 g2 = *(const float2*)(gb2 + b * OUT + o2);
    for (int i = 0; i < 16; ++i) {
        const int h = blockIdx.y * 64 + w * 16 + i;
        const int idx = (b * HID + h) * OUT + o2;
        const float2 dw = *(const float2*)(dW1 + idx);
        const float2 w1 = *(const float2*)(W1 + h * OUT + o2);
        const float wx = w1.x + dw.x;
        const float wy = w1.y + dw.y;
        float part = g2.x * wx + g2.y * wy;
        for (int off = 32; off; off >>= 1) part += __shfl_xor(part, off, 64);
        const float th = tanhv[b * HID + h];
        float2 nd;
        nd.x = dw.x - LR * th * g2.x;
        nd.y = dw.y - LR * th * g2.y;
        *(float2*)(out_dW1 + idx) = nd;
        if (lane == 0) {
            const float gbv = (1.f - th * th) * part;
            gb[b * HID + h] = gbv;
            out_db0[b * HID + h] = db0[b * HID + h] - LR * gbv;
        }
    }
}

// ---- new_d_weights_0 = dW0 - LR * x[b,q] * gb[b,h]  (float4 elementwise)
__global__ void k_upd0(const float* __restrict__ dW0, const float* __restrict__ x,
                       const float* __restrict__ gb, float* __restrict__ out_dW0) {
    const int n4 = B * IN * HID / 4;     // 16,777,216
    const int stride = gridDim.x * blockDim.x;
    for (int i = blockIdx.x * blockDim.x + threadIdx.x; i < n4; i += stride) {
        const int h4 = i & (HID / 4 - 1);        // 0..127
        const int rest = i >> 7;
        const int q = rest & (IN - 1);
        const int b = rest >> 11;
        const float4 dw = ((const float4*)dW0)[i];
        const float xv = x[b * IN + q];
        const float4 g = *(const float4*)(gb + b * HID + h4 * 4);
        float4 o;
        o.x = dw.x - LR * xv * g.x;
        o.y = dw.y - LR * xv * g.y;
        o.z = dw.z - LR * xv * g.z;
        o.w = dw.w - LR * xv * g.w;
        ((float4*)out_dW0)[i] = o;
    }
}

extern "C" void kernel_launch(void* const* d_in, const int* in_sizes, int n_in,
                              void* d_out, int out_size, void* d_ws, size_t ws_size,
                              hipStream_t stream) {
    (void)in_sizes; (void)n_in; (void)out_size; (void)ws_size;
    const float* x   = (const float*)d_in[0];
    const float* ut  = (const float*)d_in[1];
    const float* W0  = (const float*)d_in[2];
    const float* b0  = (const float*)d_in[3];
    const float* W1  = (const float*)d_in[4];
    const float* b1  = (const float*)d_in[5];
    const float* dW0 = (const float*)d_in[6];
    const float* db0 = (const float*)d_in[7];
    const float* dW1 = (const float*)d_in[8];
    const float* db1 = (const float*)d_in[9];

    float* ws  = (float*)d_ws;
    float* out = (float*)d_out;

    // zero the two accumulators (z @0, zo @32768 — contiguous)
    hipMemsetAsync(ws, 0, (size_t)(WS_ZO + B * OUT) * sizeof(float), stream);

    k_fwd1<<<dim3(B, 32), 128, 0, stream>>>(x, W0, dW0, ws + WS_Z);
    k_tanh<<<dim3(128), 256, 0, stream>>>(ws + WS_Z, b0, db0, ws + WS_TANH);
    k_fwd2<<<dim3(B, 8), 128, 0, stream>>>(ws + WS_TANH, W1, dW1, ws + WS_ZO);
    k_mid<<<dim3(B), 128, 0, stream>>>(ws + WS_ZO, b1, db1, ut,
                                       out + O_L2N, out + O_DB1, ws + WS_GB2);
    k_bwd1<<<dim3(B, 8), 256, 0, stream>>>(W1, dW1, ws + WS_GB2, ws + WS_TANH, db0,
                                           out + O_DW1, out + O_DB0, ws + WS_GB);
    k_upd0<<<dim3(4096), 256, 0, stream>>>(dW0, x, ws + WS_GB, out + O_DW0);
}

// Round 3
// 164.171 us; speedup vs baseline: 1.2239x; 1.2239x over previous
//
#include <hip/hip_runtime.h>
#include <math.h>

#define LR 0.001f

// Sizes
#define B   64
#define IN  2048
#define HID 512
#define OUT 128
#define QC  16          // q-chunks for layer-1 partials

typedef float vf2 __attribute__((ext_vector_type(2)));
typedef float vf4 __attribute__((ext_vector_type(4)));

// ws layout (floats)
#define WS_ZP    0                       // [B][QC][HID] = 524288
#define WS_TANH  (WS_ZP + B*QC*HID)      // [B][HID]     = 32768
#define WS_ZOP   (WS_TANH + B*HID)       // [B][8][OUT]  = 65536
#define WS_GB    (WS_ZOP + B*8*OUT)      // [B][HID]     = 32768

// out layout (floats)
#define O_L2N   0
#define O_DW0   (B*OUT)
#define O_DB0   (O_DW0 + B*IN*HID)
#define O_DW1   (O_DB0 + B*HID)
#define O_DB1   (O_DW1 + B*HID*OUT)

// ---- layer-1 forward partials: zp[b,qc,h] = sum_{q in chunk} x[b,q]*(W0[q,h]+dW0[b,q,h])
// grid (B, QC), block 128; each thread owns 4 h (float4), each block 128 q rows.
__global__ void k_fwd1(const float* __restrict__ x, const float* __restrict__ W0,
                       const float* __restrict__ dW0, float* __restrict__ zp) {
    const int b = blockIdx.x;
    const int q0 = blockIdx.y * (IN / QC);
    const int h = threadIdx.x * 4;        // 0..508
    const float* xr = x + b * IN;
    float4 acc = make_float4(0.f, 0.f, 0.f, 0.f);
    for (int qi = 0; qi < IN / QC; ++qi) {
        const int q = q0 + qi;
        const float xv = xr[q];
        const float4 w0 = *(const float4*)(W0 + q * HID + h);
        const float4 dw = *(const float4*)(dW0 + ((size_t)(b * IN + q)) * HID + h);
        acc.x += xv * (w0.x + dw.x);
        acc.y += xv * (w0.y + dw.y);
        acc.z += xv * (w0.z + dw.z);
        acc.w += xv * (w0.w + dw.w);
    }
    *(float4*)(zp + (b * QC + blockIdx.y) * HID + h) = acc;
}

// ---- layer-2 forward (+ fused bias/tanh): zop[b,yc,o] = sum_h tanh[b,h]*(W1[h,o]+dW1[b,h,o])
// grid (B, 8), block 128; each block owns 64 h rows, one o per thread.
__global__ void k_fwd2(const float* __restrict__ zp, const float* __restrict__ b0,
                       const float* __restrict__ db0, const float* __restrict__ W1,
                       const float* __restrict__ dW1, float* __restrict__ tanhv,
                       float* __restrict__ zop) {
    const int b = blockIdx.x;
    const int h0 = blockIdx.y * 64;
    const int tid = threadIdx.x;
    __shared__ float sth[64];
    if (tid < 64) {
        const int h = h0 + tid;
        float zsum = 0.f;
        const float* p = zp + (b * QC) * HID + h;
        #pragma unroll
        for (int qc = 0; qc < QC; ++qc) zsum += p[qc * HID];
        const float th = tanhf(zsum + b0[h] + db0[b * HID + h]);
        tanhv[b * HID + h] = th;
        sth[tid] = th;
    }
    __syncthreads();
    const int o = tid;
    float acc = 0.f;
    #pragma unroll 8
    for (int hi = 0; hi < 64; ++hi) {
        const int h = h0 + hi;
        acc += sth[hi] * (W1[h * OUT + o] + dW1[(b * HID + h) * OUT + o]);
    }
    zop[(b * 8 + blockIdx.y) * OUT + o] = acc;
}

// ---- fused middle + backward layer 2:
// recompute row stats per wave (redundant, cheap), g_b2, then g_b, new_dW1, new_db0;
// block (b, y==0) wave 0 also writes l2_normed_out2 and new_d_bias_1.
// grid (B, 8), block 256 (4 waves); each wave owns 16 h rows; lane owns 2 o.
__global__ void k_bwd1(const float* __restrict__ zop, const float* __restrict__ b1,
                       const float* __restrict__ db1, const float* __restrict__ ut,
                       const float* __restrict__ W1, const float* __restrict__ dW1,
                       const float* __restrict__ tanhv, const float* __restrict__ db0,
                       float* __restrict__ out_l2n, float* __restrict__ out_db1,
                       float* __restrict__ out_dW1, float* __restrict__ out_db0,
                       float* __restrict__ gb) {
    const int b = blockIdx.x;
    const int w = threadIdx.x >> 6;
    const int lane = threadIdx.x & 63;
    const int o2 = lane * 2;

    // out2 at (o2, o2+1) + full-row reductions (each wave redundantly)
    float2 zo;
    zo.x = b1[o2]     + db1[b * OUT + o2];
    zo.y = b1[o2 + 1] + db1[b * OUT + o2 + 1];
    #pragma unroll
    for (int c = 0; c < 8; ++c) {
        const float2 zp2 = *(const float2*)(zop + (b * 8 + c) * OUT + o2);
        zo.x += zp2.x; zo.y += zp2.y;
    }
    const float2 tr = *(const float2*)(ut + b * OUT + o2);
    float a = zo.x * zo.x + zo.y * zo.y;
    float c2 = tr.x * tr.x + tr.y * tr.y;
    float d  = tr.x * zo.x + tr.y * zo.y;
    for (int off = 32; off; off >>= 1) {
        a  += __shfl_xor(a,  off, 64);
        c2 += __shfl_xor(c2, off, 64);
        d  += __shfl_xor(d,  off, 64);
    }
    const float l2 = a;                               // squared norm (as in source)
    const float nt = fmaxf(sqrtf(c2), 1e-12f);        // ||update_target||
    const float tdot = d / nt;                        // sum(t * out2)
    const float s = 2.0f * tdot / (l2 * l2);
    float2 g2;
    g2.x = -(tr.x / nt) / l2 + s * zo.x;
    g2.y = -(tr.y / nt) / l2 + s * zo.y;

    if (blockIdx.y == 0 && w == 0) {
        *(float2*)(out_l2n + b * OUT + o2) = make_float2(zo.x / l2, zo.y / l2);
        *(float2*)(out_db1 + b * OUT + o2) =
            make_float2(db1[b * OUT + o2] - LR * g2.x, db1[b * OUT + o2 + 1] - LR * g2.y);
    }

    // backward through layer 2
    for (int i = 0; i < 16; ++i) {
        const int h = blockIdx.y * 64 + w * 16 + i;
        const int idx = (b * HID + h) * OUT + o2;
        const float2 dw = *(const float2*)(dW1 + idx);
        const float2 w1 = *(const float2*)(W1 + h * OUT + o2);
        float part = g2.x * (w1.x + dw.x) + g2.y * (w1.y + dw.y);
        for (int off = 32; off; off >>= 1) part += __shfl_xor(part, off, 64);
        const float th = tanhv[b * HID + h];
        vf2 nd;
        nd.x = dw.x - LR * th * g2.x;
        nd.y = dw.y - LR * th * g2.y;
        __builtin_nontemporal_store(nd, (vf2*)(out_dW1 + idx));
        if (lane == 0) {
            const float gbv = (1.f - th * th) * part;
            gb[b * HID + h] = gbv;
            out_db0[b * HID + h] = db0[b * HID + h] - LR * gbv;
        }
    }
}

// ---- new_d_weights_0 = dW0 - LR * x[b,q] * gb[b,h]
// REVERSED traversal: k_fwd1 streamed dW0 front-to-back, so the tail is
// L3-resident; reading back-to-front converts LRU thrash into hits.
// Nontemporal stores keep the 268MB output stream from evicting dW0 lines.
__global__ void k_upd0(const float* __restrict__ dW0, const float* __restrict__ x,
                       const float* __restrict__ gb, float* __restrict__ out_dW0) {
    const int n4 = B * IN * HID / 4;     // 16,777,216
    const int stride = gridDim.x * blockDim.x;
    for (int i = blockIdx.x * blockDim.x + threadIdx.x; i < n4; i += stride) {
        const int j = n4 - 1 - i;                // reversed
        const int h4 = j & (HID / 4 - 1);        // 0..127
        const int rest = j >> 7;
        const int q = rest & (IN - 1);
        const int b = rest >> 11;
        const float4 dw = ((const float4*)dW0)[j];
        const float xv = x[b * IN + q];
        const float4 g = *(const float4*)(gb + b * HID + h4 * 4);
        vf4 o;
        o.x = dw.x - LR * xv * g.x;
        o.y = dw.y - LR * xv * g.y;
        o.z = dw.z - LR * xv * g.z;
        o.w = dw.w - LR * xv * g.w;
        __builtin_nontemporal_store(o, (vf4*)out_dW0 + j);
    }
}

extern "C" void kernel_launch(void* const* d_in, const int* in_sizes, int n_in,
                              void* d_out, int out_size, void* d_ws, size_t ws_size,
                              hipStream_t stream) {
    (void)in_sizes; (void)n_in; (void)out_size; (void)ws_size;
    const float* x   = (const float*)d_in[0];
    const float* ut  = (const float*)d_in[1];
    const float* W0  = (const float*)d_in[2];
    const float* b0  = (const float*)d_in[3];
    const float* W1  = (const float*)d_in[4];
    const float* b1  = (const float*)d_in[5];
    const float* dW0 = (const float*)d_in[6];
    const float* db0 = (const float*)d_in[7];
    const float* dW1 = (const float*)d_in[8];
    const float* db1 = (const float*)d_in[9];

    float* ws  = (float*)d_ws;
    float* out = (float*)d_out;

    k_fwd1<<<dim3(B, QC), 128, 0, stream>>>(x, W0, dW0, ws + WS_ZP);
    k_fwd2<<<dim3(B, 8), 128, 0, stream>>>(ws + WS_ZP, b0, db0, W1, dW1,
                                           ws + WS_TANH, ws + WS_ZOP);
    k_bwd1<<<dim3(B, 8), 256, 0, stream>>>(ws + WS_ZOP, b1, db1, ut, W1, dW1,
                                           ws + WS_TANH, db0,
                                           out + O_L2N, out + O_DB1,
                                           out + O_DW1, out + O_DB0, ws + WS_GB);
    k_upd0<<<dim3(4096), 256, 0, stream>>>(dW0, x, ws + WS_GB, out + O_DW0);
}